// Round 1
// 563.322 us; speedup vs baseline: 1.0751x; 1.0751x over previous
//
#include <hip/hip_runtime.h>
#include <hip/hip_bf16.h>
#include <math.h>

#define DM 1024
#define NH 16
#define DK 64
#define BB 4
#define SS 2048
#define EPSV 1e-6f
#define NE ((size_t)BB * SS * DM)  // 8388608
#define MM ((size_t)DM * DM)       // 1048576
// 0.125 * log2(e): folded into w_q so softmax is a raw exp2
#define QSCALE 0.18033688011112042f

typedef __attribute__((ext_vector_type(8))) short short8;
typedef __attribute__((ext_vector_type(4))) float f32x4;

__device__ inline unsigned short f2bf(float x) {
  unsigned int u = __builtin_bit_cast(unsigned int, x);
  u += 0x7FFF + ((u >> 16) & 1);  // RNE
  return (unsigned short)(u >> 16);
}
__device__ inline ushort4 f2bf4(float4 v) {
  ushort4 r;
  r.x = f2bf(v.x); r.y = f2bf(v.y); r.z = f2bf(v.z); r.w = f2bf(v.w);
  return r;
}

__device__ inline float fexp2(float x) {
#if __has_builtin(__builtin_amdgcn_exp2f)
  return __builtin_amdgcn_exp2f(x);
#else
  return exp2f(x);
#endif
}

// pack 2 f32 -> 1 dword of 2 bf16 (lo=a, hi=b)
__device__ inline unsigned cvtpk_bf16(float a, float b) {
  unsigned r;
  asm("v_cvt_pk_bf16_f32 %0, %1, %2" : "=v"(r) : "v"(a), "v"(b));
  return r;
}

// async global->LDS, 16B per lane; LDS dest = wave-uniform base + lane*16
__device__ inline void gl_lds16(const unsigned short* g, unsigned short* l) {
  __builtin_amdgcn_global_load_lds((const __attribute__((address_space(1))) void*)g,
                                   (__attribute__((address_space(3))) void*)l, 16, 0, 0);
}

// ---- Pre-pass: x tensors f32 -> bf16 (elementwise, float4) ----
__global__ __launch_bounds__(256) void cvt_x_k(const float* __restrict__ xq,
                                               const float* __restrict__ xk,
                                               const float* __restrict__ xv,
                                               unsigned short* __restrict__ oq,
                                               unsigned short* __restrict__ ok,
                                               unsigned short* __restrict__ ov) {
  const size_t NF4 = NE / 4;
  size_t g = (size_t)blockIdx.x * 256 + threadIdx.x;
  int t = (int)(g / NF4);
  size_t i = g - (size_t)t * NF4;
  const float* s = (t == 0) ? xq : (t == 1) ? xk : xv;
  unsigned short* d = (t == 0) ? oq : (t == 1) ? ok : ov;
  float4 v = ((const float4*)s)[i];
  ((ushort4*)d)[i] = f2bf4(v);
}

// ---- Pre-pass: W[k][n] f32 -> WT[n][k] bf16 (LDS transpose); w_q gets QSCALE ----
__global__ __launch_bounds__(256) void cvt_wT_k(const float* __restrict__ w0,
                                                const float* __restrict__ w1,
                                                const float* __restrict__ w2,
                                                const float* __restrict__ w3,
                                                unsigned short* __restrict__ o0,
                                                unsigned short* __restrict__ o1,
                                                unsigned short* __restrict__ o2,
                                                unsigned short* __restrict__ o3) {
  __shared__ float t[32][33];
  int z = blockIdx.z;
  const float* w = (z == 0) ? w0 : (z == 1) ? w1 : (z == 2) ? w2 : w3;
  unsigned short* o = (z == 0) ? o0 : (z == 1) ? o1 : (z == 2) ? o2 : o3;
  float sc = (z == 0) ? QSCALE : 1.0f;
  int n0 = blockIdx.x * 32, k0 = blockIdx.y * 32;
  int tx = threadIdx.x & 31, ty = threadIdx.x >> 5;
#pragma unroll
  for (int s = 0; s < 4; ++s) t[ty + s * 8][tx] = w[(size_t)(k0 + ty + s * 8) * DM + n0 + tx];
  __syncthreads();
#pragma unroll
  for (int s = 0; s < 4; ++s)
    o[(size_t)(n0 + ty + s * 8) * DM + k0 + tx] = f2bf(t[tx][ty + s * 8] * sc);
}

// ---- Pre-pass: pack int32 mask -> 1 bit ----
__global__ __launch_bounds__(256) void maskbits_k(const int* __restrict__ mask,
                                                  unsigned long long* __restrict__ bm) {
  const int total = BB * SS * (SS / 64);
  int lane = threadIdx.x & 63;
  int wid = (blockIdx.x * 256 + threadIdx.x) >> 6;
  int nw = (gridDim.x * 256) >> 6;
  for (int w = wid; w < total; w += nw) {
    int v = mask[(size_t)w * 64 + lane];
    unsigned long long bal = __ballot(v != 0);
    if (lane == 0) bm[w] = bal;
  }
}

// ---- m97-style MFMA GEMM: C = A[M,K] @ WT[N,K]^T, bf16 in, 128x128 tile, BK=32.
template <bool BF16OUT>
__global__ __launch_bounds__(256) void gemm_lds_k(const unsigned short* __restrict__ Abase,
                                                  const unsigned short* __restrict__ WTbase,
                                                  void* __restrict__ Cv, int M, int N, int K,
                                                  size_t zA, size_t zW, size_t zC) {
  __shared__ __align__(16) unsigned short As[128 * 32];
  __shared__ __align__(16) unsigned short Bs[128 * 32];
  const unsigned short* A = Abase + (size_t)blockIdx.z * zA;
  const unsigned short* WT = WTbase + (size_t)blockIdx.z * zW;
  int bm = blockIdx.y * 128, bn = blockIdx.x * 128;
  int tid = threadIdx.x, lane = tid & 63, w = tid >> 6;
  int quad = lane >> 4, c = lane & 15, wx = w & 1, wy = w >> 1;

  f32x4 acc[4][4];
#pragma unroll
  for (int mt = 0; mt < 4; ++mt)
#pragma unroll
    for (int nt = 0; nt < 4; ++nt)
#pragma unroll
      for (int r = 0; r < 4; ++r) acc[mt][nt][r] = 0.f;

  int srow = lane >> 2, scol = (lane & 3) * 8;
  const unsigned short* Ag = A + (size_t)(bm + w * 32 + srow) * K + scol;
  const unsigned short* Bg = WT + (size_t)(bn + w * 32 + srow) * K + scol;
  unsigned short* Al = &As[w * 32 * 32];
  unsigned short* Bl = &Bs[w * 32 * 32];

  for (int k0 = 0; k0 < K; k0 += 32) {
    gl_lds16(Ag + k0, Al);
    gl_lds16(Ag + (size_t)16 * K + k0, Al + 16 * 32);
    gl_lds16(Bg + k0, Bl);
    gl_lds16(Bg + (size_t)16 * K + k0, Bl + 16 * 32);
    __syncthreads();  // drains vmcnt -> LDS valid
    short8 af[4], bf[4];
#pragma unroll
    for (int mt = 0; mt < 4; ++mt) af[mt] = *(const short8*)&As[(wy * 64 + mt * 16 + c) * 32 + quad * 8];
#pragma unroll
    for (int nt = 0; nt < 4; ++nt) bf[nt] = *(const short8*)&Bs[(wx * 64 + nt * 16 + c) * 32 + quad * 8];
#pragma unroll
    for (int mt = 0; mt < 4; ++mt)
#pragma unroll
      for (int nt = 0; nt < 4; ++nt)
        acc[mt][nt] = __builtin_amdgcn_mfma_f32_16x16x32_bf16(af[mt], bf[nt], acc[mt][nt], 0, 0, 0);
    __syncthreads();
  }
#pragma unroll
  for (int mt = 0; mt < 4; ++mt)
#pragma unroll
    for (int nt = 0; nt < 4; ++nt)
#pragma unroll
      for (int r = 0; r < 4; ++r) {
        size_t idx = (size_t)blockIdx.z * zC +
                     (size_t)(bm + wy * 64 + mt * 16 + quad * 4 + r) * N + bn + wx * 64 + nt * 16 + c;
        if (BF16OUT)
          ((unsigned short*)Cv)[idx] = f2bf(acc[mt][nt][r]);
        else
          ((float*)Cv)[idx] = acc[mt][nt][r];
      }
}

// ---- MFMA flash attention, swapped-QK^T: P stays in registers.
// sacc = mfma(K_frag, Q_frag) => lane (c,quad) holds S[q=c][k=nt*16+quad*4+r].
// V rows staged PERMUTED (pi(32s+8w+j) = 32s+16*(j>>2)+4w+(j&3)) so the PV
// A-operand k-order matches the lane-local P order => zero cross-lane traffic.
__global__ __launch_bounds__(256) void attn_mfma_k(const unsigned short* __restrict__ Q,
                                                   const unsigned short* __restrict__ Kg,
                                                   const unsigned short* __restrict__ V,
                                                   const unsigned long long* __restrict__ bm,
                                                   unsigned short* __restrict__ O) {
  __shared__ __align__(16) unsigned short Ks[64 * 72];
  __shared__ __align__(16) unsigned short VB[64 * 64];
  int b = blockIdx.z, h = blockIdx.y, q0 = blockIdx.x * 64;
  int tid = threadIdx.x, lane = tid & 63, w = tid >> 6;
  int quad = lane >> 4, c = lane & 15;

  short8 qf[2];
  {
    const unsigned short* qp = Q + ((size_t)b * SS + q0 + w * 16 + c) * DM + h * DK + quad * 8;
    qf[0] = *(const short8*)qp;
    qf[1] = *(const short8*)(qp + 32);
  }
  // per-lane mask row pointer: lane owns q-row q0 + w*16 + c
  const unsigned long long* bp = bm + ((size_t)b * SS + q0 + w * 16 + c) * (SS / 64);
  const int shq = quad * 4;

  float lsum = 0.f;
  f32x4 accO[4];
#pragma unroll
  for (int dt = 0; dt < 4; ++dt)
#pragma unroll
    for (int r = 0; r < 4; ++r) accO[dt][r] = 0.f;

  int krow = tid >> 3, kd = (tid & 7) * 8;
  int vd = tid & 63, vdt = vd >> 4, vc = vd & 15;

  for (int kt = 0; kt < SS / 64; ++kt) {
    int k0 = kt * 64;
    // K tile -> LDS (row-major, pad 72)
#pragma unroll
    for (int pass = 0; pass < 2; ++pass) {
      int kr = krow + pass * 32;
      short8 kv = *(const short8*)&Kg[((size_t)b * SS + k0 + kr) * DM + h * DK + kd];
      *(short8*)&Ks[kr * 72 + kd] = kv;
    }
    // V tile -> VB with permuted k-rows (same instruction count as before)
    const unsigned short* vtile = &V[((size_t)b * SS + k0) * DM + h * DK + vd];
#pragma unroll
    for (int s = 0; s < 2; ++s) {
      union { short8 v; unsigned short u[8]; } pk;
#pragma unroll
      for (int j = 0; j < 8; ++j)
        pk.u[j] = vtile[(size_t)(s * 32 + (j >> 2) * 16 + w * 4 + (j & 3)) * DM];
      *(short8*)&VB[((s * 4 + vdt) * 4 + w) * 128 + vc * 8] = pk.v;
    }
    __syncthreads();

    // QK^T swapped: A=K rows (k-dim), B=Q cols (q-dim) -> S^T layout
    f32x4 sacc[4];
#pragma unroll
    for (int nt = 0; nt < 4; ++nt)
#pragma unroll
      for (int r = 0; r < 4; ++r) sacc[nt][r] = 0.f;
#pragma unroll
    for (int dkt = 0; dkt < 2; ++dkt)
#pragma unroll
      for (int nt = 0; nt < 4; ++nt) {
        short8 kfrag = *(const short8*)&Ks[(nt * 16 + c) * 72 + dkt * 32 + quad * 8];
        sacc[nt] = __builtin_amdgcn_mfma_f32_16x16x32_bf16(kfrag, qf[dkt], sacc[nt], 0, 0, 0);
      }

    // in-register softmax numerator; scores pre-scaled by 0.125*log2e via w_q
    unsigned long long mwv = bp[kt];
    unsigned long long msh = mwv >> shq;
    unsigned mlo = (unsigned)msh, mhi = (unsigned)(msh >> 32);
    unsigned padw[8];
#pragma unroll
    for (int nt = 0; nt < 4; ++nt) {
      unsigned msel = (nt & 2) ? mhi : mlo;
      const int bse = (nt & 1) * 16;
      float pv[4];
#pragma unroll
      for (int r = 0; r < 4; ++r) {
        float ex = fexp2(sacc[nt][r]);
        pv[r] = ((msel >> (bse + r)) & 1u) ? ex : 1.0f;  // masked -> exp(eps) ~ 1
        lsum += pv[r];
      }
      padw[nt * 2] = cvtpk_bf16(pv[0], pv[1]);
      padw[nt * 2 + 1] = cvtpk_bf16(pv[2], pv[3]);
    }

    // PV: A = lane-local packed P, B = permuted-V fragments
#pragma unroll
    for (int pkt = 0; pkt < 2; ++pkt) {
      union { unsigned u[4]; short8 s8; } pa;
      pa.u[0] = padw[pkt * 4 + 0];
      pa.u[1] = padw[pkt * 4 + 1];
      pa.u[2] = padw[pkt * 4 + 2];
      pa.u[3] = padw[pkt * 4 + 3];
#pragma unroll
      for (int dt = 0; dt < 4; ++dt) {
        short8 vf = *(const short8*)&VB[((pkt * 4 + dt) * 4 + quad) * 128 + c * 8];
        accO[dt] = __builtin_amdgcn_mfma_f32_16x16x32_bf16(pa.s8, vf, accO[dt], 0, 0, 0);
      }
    }
    __syncthreads();
  }

  // row-sum lives per lane (q=c); reduce across quads, then broadcast to C layout
  float l = lsum;
  l += __shfl_xor(l, 16);
  l += __shfl_xor(l, 32);
  float inv[4];
#pragma unroll
  for (int r = 0; r < 4; ++r) inv[r] = 1.f / __shfl(l, quad * 4 + r);
#pragma unroll
  for (int dt = 0; dt < 4; ++dt)
#pragma unroll
    for (int r = 0; r < 4; ++r) {
      int q = q0 + w * 16 + quad * 4 + r;
      O[((size_t)b * SS + q) * DM + h * DK + dt * 16 + c] = f2bf(accO[dt][r] * inv[r]);
    }
}

// ---- Residual + LayerNorm (ddof=1, eps on std), vectorized ----
__global__ __launch_bounds__(256) void ln_k(const float* __restrict__ P,
                                            const float* __restrict__ X,
                                            const float* __restrict__ gamma,
                                            const float* __restrict__ beta,
                                            float* __restrict__ out) {
  __shared__ float sm[4];
  int row = blockIdx.x, tid = threadIdx.x, w = tid >> 6;
  float4 p = ((const float4*)(P + (size_t)row * DM))[tid];
  float4 x = ((const float4*)(X + (size_t)row * DM))[tid];
  float4 v = make_float4(p.x + x.x, p.y + x.y, p.z + x.z, p.w + x.w);
  float s = (v.x + v.y) + (v.z + v.w);
#pragma unroll
  for (int off = 1; off < 64; off <<= 1) s += __shfl_xor(s, off);
  if ((tid & 63) == 0) sm[w] = s;
  __syncthreads();
  float mean = (sm[0] + sm[1] + sm[2] + sm[3]) * (1.f / DM);
  __syncthreads();
  float dx = v.x - mean, dy = v.y - mean, dz = v.z - mean, dw = v.w - mean;
  float s2 = (dx * dx + dy * dy) + (dz * dz + dw * dw);
#pragma unroll
  for (int off = 1; off < 64; off <<= 1) s2 += __shfl_xor(s2, off);
  if ((tid & 63) == 0) sm[w] = s2;
  __syncthreads();
  float var = (sm[0] + sm[1] + sm[2] + sm[3]) * (1.f / (DM - 1));
  float inv = 1.f / (sqrtf(var) + EPSV);
  float4 g = ((const float4*)gamma)[tid];
  float4 be = ((const float4*)beta)[tid];
  float4 y = make_float4(g.x * dx * inv + be.x, g.y * dy * inv + be.y,
                         g.z * dz * inv + be.z, g.w * dw * inv + be.w);
  ((float4*)(out + (size_t)row * DM))[tid] = y;
}

extern "C" void kernel_launch(void* const* d_in, const int* in_sizes, int n_in,
                              void* d_out, int out_size, void* d_ws, size_t ws_size,
                              hipStream_t stream) {
  const float* xq = (const float*)d_in[0];
  const float* xk = (const float*)d_in[1];
  const float* xv = (const float*)d_in[2];
  const int* mask = (const int*)d_in[3];
  const float* wq = (const float*)d_in[4];
  const float* wk = (const float*)d_in[5];
  const float* wv = (const float*)d_in[6];
  const float* w0 = (const float*)d_in[7];
  const float* gamma = (const float*)d_in[8];
  const float* beta = (const float*)d_in[9];
  float* out = (float*)d_out;

  // ws: [xqb NE][xkb NE][xvb NE][wTq MM][wTk MM][wTv MM][wT0 MM][Qb NE][Kb NE][Vb NE][AOb NE]
  // P (f32, NE) overlays Qb+Kb (dead after attention).
  unsigned short* xqb = (unsigned short*)d_ws;
  unsigned short* xkb = xqb + NE;
  unsigned short* xvb = xkb + NE;
  unsigned short* wTq = xvb + NE;
  unsigned short* wTk = wTq + MM;
  unsigned short* wTv = wTk + MM;
  unsigned short* wT0 = wTv + MM;
  unsigned short* Qb = wT0 + MM;
  unsigned short* Kb = Qb + NE;
  unsigned short* Vb = Kb + NE;
  unsigned short* AOb = Vb + NE;
  float* P = (float*)Qb;
  unsigned long long* bm = (unsigned long long*)d_out;  // 2 MB, dead before ln_k writes

  const int M = BB * SS;  // 8192
  cvt_x_k<<<(unsigned)(3 * (NE / 4) / 256), 256, 0, stream>>>(xq, xk, xv, xqb, xkb, xvb);
  cvt_wT_k<<<dim3(32, 32, 4), 256, 0, stream>>>(wq, wk, wv, w0, wTq, wTk, wTv, wT0);
  maskbits_k<<<256, 256, 0, stream>>>(mask, bm);
  gemm_lds_k<true><<<dim3(DM / 128, M / 128, 3), 256, 0, stream>>>(
      xqb, wTq, Qb, M, DM, DM, NE, MM, NE);
  attn_mfma_k<<<dim3(SS / 64, NH, BB), 256, 0, stream>>>(Qb, Kb, Vb, bm, AOb);
  gemm_lds_k<false><<<dim3(DM / 128, M / 128, 1), 256, 0, stream>>>(
      AOb, wT0, P, M, DM, DM, 0, 0, 0);
  ln_k<<<M, 256, 0, stream>>>(P, xq, gamma, beta, out);
}

// Round 4
// 550.448 us; speedup vs baseline: 1.1002x; 1.0234x over previous
//
#include <hip/hip_runtime.h>
#include <hip/hip_bf16.h>
#include <math.h>

#define DM 1024
#define NH 16
#define DK 64
#define BB 4
#define SS 2048
#define EPSV 1e-6f
#define NE ((size_t)BB * SS * DM)  // 8388608
#define MM ((size_t)DM * DM)       // 1048576
// 0.125 * log2(e): folded into w_q so softmax is a raw exp2
#define QSCALE 0.18033688011112042f

typedef __attribute__((ext_vector_type(8))) short short8;
typedef __attribute__((ext_vector_type(4))) float f32x4;

__device__ inline unsigned short f2bf(float x) {
  unsigned int u = __builtin_bit_cast(unsigned int, x);
  u += 0x7FFF + ((u >> 16) & 1);  // RNE
  return (unsigned short)(u >> 16);
}
__device__ inline ushort4 f2bf4(float4 v) {
  ushort4 r;
  r.x = f2bf(v.x); r.y = f2bf(v.y); r.z = f2bf(v.z); r.w = f2bf(v.w);
  return r;
}

__device__ inline float fexp2(float x) {
#if __has_builtin(__builtin_amdgcn_exp2f)
  return __builtin_amdgcn_exp2f(x);
#else
  return exp2f(x);
#endif
}

// pack 2 f32 -> 1 dword of 2 bf16 (lo=a, hi=b)
__device__ inline unsigned cvtpk_bf16(float a, float b) {
  unsigned r;
  asm("v_cvt_pk_bf16_f32 %0, %1, %2" : "=v"(r) : "v"(a), "v"(b));
  return r;
}

// async global->LDS, 16B per lane; LDS dest = wave-uniform base + lane*16
__device__ inline void gl_lds16(const unsigned short* g, unsigned short* l) {
  __builtin_amdgcn_global_load_lds((const __attribute__((address_space(1))) void*)g,
                                   (__attribute__((address_space(3))) void*)l, 16, 0, 0);
}

// ---- Pre-pass: x tensors f32 -> bf16 (elementwise, float4) ----
__global__ __launch_bounds__(256) void cvt_x_k(const float* __restrict__ xq,
                                               const float* __restrict__ xk,
                                               const float* __restrict__ xv,
                                               unsigned short* __restrict__ oq,
                                               unsigned short* __restrict__ ok,
                                               unsigned short* __restrict__ ov) {
  const size_t NF4 = NE / 4;
  size_t g = (size_t)blockIdx.x * 256 + threadIdx.x;
  int t = (int)(g / NF4);
  size_t i = g - (size_t)t * NF4;
  const float* s = (t == 0) ? xq : (t == 1) ? xk : xv;
  unsigned short* d = (t == 0) ? oq : (t == 1) ? ok : ov;
  float4 v = ((const float4*)s)[i];
  ((ushort4*)d)[i] = f2bf4(v);
}

// ---- Pre-pass: W[k][n] f32 -> WT[n][k] bf16 (LDS transpose); w_q gets QSCALE ----
__global__ __launch_bounds__(256) void cvt_wT_k(const float* __restrict__ w0,
                                                const float* __restrict__ w1,
                                                const float* __restrict__ w2,
                                                const float* __restrict__ w3,
                                                unsigned short* __restrict__ o0,
                                                unsigned short* __restrict__ o1,
                                                unsigned short* __restrict__ o2,
                                                unsigned short* __restrict__ o3) {
  __shared__ float t[32][33];
  int z = blockIdx.z;
  const float* w = (z == 0) ? w0 : (z == 1) ? w1 : (z == 2) ? w2 : w3;
  unsigned short* o = (z == 0) ? o0 : (z == 1) ? o1 : (z == 2) ? o2 : o3;
  float sc = (z == 0) ? QSCALE : 1.0f;
  int n0 = blockIdx.x * 32, k0 = blockIdx.y * 32;
  int tx = threadIdx.x & 31, ty = threadIdx.x >> 5;
#pragma unroll
  for (int s = 0; s < 4; ++s) t[ty + s * 8][tx] = w[(size_t)(k0 + ty + s * 8) * DM + n0 + tx];
  __syncthreads();
#pragma unroll
  for (int s = 0; s < 4; ++s)
    o[(size_t)(n0 + ty + s * 8) * DM + k0 + tx] = f2bf(t[tx][ty + s * 8] * sc);
}

// ---- Pre-pass: pack int32 mask -> 1 bit ----
__global__ __launch_bounds__(256) void maskbits_k(const int* __restrict__ mask,
                                                  unsigned long long* __restrict__ bm) {
  const int total = BB * SS * (SS / 64);
  int lane = threadIdx.x & 63;
  int wid = (blockIdx.x * 256 + threadIdx.x) >> 6;
  int nw = (gridDim.x * 256) >> 6;
  for (int w = wid; w < total; w += nw) {
    int v = mask[(size_t)w * 64 + lane];
    unsigned long long bal = __ballot(v != 0);
    if (lane == 0) bm[w] = bal;
  }
}

// ---- m97-style MFMA GEMM: C = A[M,K] @ WT[N,K]^T, bf16 in, 128x128 tile, BK=32.
template <bool BF16OUT>
__global__ __launch_bounds__(256) void gemm_lds_k(const unsigned short* __restrict__ Abase,
                                                  const unsigned short* __restrict__ WTbase,
                                                  void* __restrict__ Cv, int M, int N, int K,
                                                  size_t zA, size_t zW, size_t zC) {
  __shared__ __align__(16) unsigned short As[128 * 32];
  __shared__ __align__(16) unsigned short Bs[128 * 32];
  const unsigned short* A = Abase + (size_t)blockIdx.z * zA;
  const unsigned short* WT = WTbase + (size_t)blockIdx.z * zW;
  int bm = blockIdx.y * 128, bn = blockIdx.x * 128;
  int tid = threadIdx.x, lane = tid & 63, w = tid >> 6;
  int quad = lane >> 4, c = lane & 15, wx = w & 1, wy = w >> 1;

  f32x4 acc[4][4];
#pragma unroll
  for (int mt = 0; mt < 4; ++mt)
#pragma unroll
    for (int nt = 0; nt < 4; ++nt)
#pragma unroll
      for (int r = 0; r < 4; ++r) acc[mt][nt][r] = 0.f;

  int srow = lane >> 2, scol = (lane & 3) * 8;
  const unsigned short* Ag = A + (size_t)(bm + w * 32 + srow) * K + scol;
  const unsigned short* Bg = WT + (size_t)(bn + w * 32 + srow) * K + scol;
  unsigned short* Al = &As[w * 32 * 32];
  unsigned short* Bl = &Bs[w * 32 * 32];

  for (int k0 = 0; k0 < K; k0 += 32) {
    gl_lds16(Ag + k0, Al);
    gl_lds16(Ag + (size_t)16 * K + k0, Al + 16 * 32);
    gl_lds16(Bg + k0, Bl);
    gl_lds16(Bg + (size_t)16 * K + k0, Bl + 16 * 32);
    __syncthreads();  // drains vmcnt -> LDS valid
    short8 af[4], bf[4];
#pragma unroll
    for (int mt = 0; mt < 4; ++mt) af[mt] = *(const short8*)&As[(wy * 64 + mt * 16 + c) * 32 + quad * 8];
#pragma unroll
    for (int nt = 0; nt < 4; ++nt) bf[nt] = *(const short8*)&Bs[(wx * 64 + nt * 16 + c) * 32 + quad * 8];
#pragma unroll
    for (int mt = 0; mt < 4; ++mt)
#pragma unroll
      for (int nt = 0; nt < 4; ++nt)
        acc[mt][nt] = __builtin_amdgcn_mfma_f32_16x16x32_bf16(af[mt], bf[nt], acc[mt][nt], 0, 0, 0);
    __syncthreads();
  }
#pragma unroll
  for (int mt = 0; mt < 4; ++mt)
#pragma unroll
    for (int nt = 0; nt < 4; ++nt)
#pragma unroll
      for (int r = 0; r < 4; ++r) {
        size_t idx = (size_t)blockIdx.z * zC +
                     (size_t)(bm + wy * 64 + mt * 16 + quad * 4 + r) * N + bn + wx * 64 + nt * 16 + c;
        if (BF16OUT)
          ((unsigned short*)Cv)[idx] = f2bf(acc[mt][nt][r]);
        else
          ((float*)Cv)[idx] = acc[mt][nt][r];
      }
}

// ---- MFMA flash attention, swapped-QK^T, P stays in registers.
// K LDS: row-major [64][8 chunks of 8] with chunk XOR swizzle (cc ^ (row&7))
//        baked into the per-lane GLOBAL source of global_load_lds (rule #21);
//        ds_read_b128 applies the same XOR. Verified by element simulation.
// V LDS: R1-PROVEN layout VB[o=16s+4dt+w][vc=16][j=8] = V[pi(32s+8w+j)][16dt+vc],
//        pi(32s+8w+j) = 32s+16*(j>>2)+4w+(j&3); staged with 4-row x 2-col uint
//        gathers (8 uint loads + 4 ds_write_b64 per thread per tile).
// Softmax fully in-register (swapped QK^T => lane owns q-row = c).
// Row-sum via ones-MFMA: lacc rows (quad*4+r) align with accO rows -> no shuffles.
__global__ __launch_bounds__(256) void attn_mfma_k(const unsigned short* __restrict__ Q,
                                                   const unsigned short* __restrict__ Kg,
                                                   const unsigned short* __restrict__ V,
                                                   const unsigned long long* __restrict__ bm,
                                                   unsigned short* __restrict__ O) {
  __shared__ __align__(16) unsigned short Ks[64 * 64];
  __shared__ __align__(16) unsigned short VB[64 * 64];
  int b = blockIdx.z, h = blockIdx.y, q0 = blockIdx.x * 64;
  int tid = threadIdx.x, lane = tid & 63, w = tid >> 6;
  int quad = lane >> 4, c = lane & 15;

  short8 qf[2];
  {
    const unsigned short* qp = Q + ((size_t)b * SS + q0 + w * 16 + c) * DM + h * DK + quad * 8;
    qf[0] = *(const short8*)qp;
    qf[1] = *(const short8*)(qp + 32);
  }
  const unsigned long long* bp = bm + ((size_t)b * SS + q0 + w * 16 + c) * (SS / 64);
  const int shq = quad * 4;

  short8 ones8;
#pragma unroll
  for (int j = 0; j < 8; ++j) ones8[j] = (short)0x3F80;  // bf16 1.0

  f32x4 accO[4], lacc;
#pragma unroll
  for (int r = 0; r < 4; ++r) lacc[r] = 0.f;
#pragma unroll
  for (int dt = 0; dt < 4; ++dt)
#pragma unroll
    for (int r = 0; r < 4; ++r) accO[dt][r] = 0.f;

  // K staging: chunk n (call0 n=tid, call1 n=tid+256): row n>>3, group (n&7)^(row&7)
  int kr = tid >> 3;
  int kcc = (tid & 7) ^ (kr & 7);
  const unsigned short* pK0 = Kg + ((size_t)b * SS + kr) * DM + h * DK + kcc * 8;
  const unsigned short* pK1 = pK0 + (size_t)32 * DM;
  unsigned short* KlA = &Ks[w * 512];
  unsigned short* KlB = &Ks[2048 + w * 512];

  // V staging decode: cp=tid&7, jh=(tid>>3)&1, vdt=(tid>>4)&3, wo=tid>>6 (=w)
  // pass s: global rows 32s+16jh+4wo+(0..3), cols 16vdt+2cp(+1)
  // LDS: o = 16s + 4vdt + wo; elems o*128 + 16cp + 4jh (lo col), +8 (hi col)
  int vcp = tid & 7, vjh = (tid >> 3) & 1, vdt = (tid >> 4) & 3;
  const unsigned short* pVg =
      V + ((size_t)b * SS + 16 * vjh + 4 * w) * DM + h * DK + 16 * vdt + 2 * vcp;
  unsigned short* vw0 = &VB[(4 * vdt + w) * 128 + 16 * vcp + 4 * vjh];

  // QK fragment read bases (swizzled): row R=nt*16+c (R&7==c&7), group g^(c&7)
  const unsigned short* kf0 = &Ks[c * 64 + ((quad ^ (c & 7)) * 8)];
  const unsigned short* kf1 = &Ks[c * 64 + (((4 + quad) ^ (c & 7)) * 8)];

  for (int kt = 0; kt < SS / 64; ++kt) {
    gl_lds16(pK0, KlA);
    gl_lds16(pK1, KlB);
    pK0 += (size_t)64 * DM; pK1 += (size_t)64 * DM;
#pragma unroll
    for (int s = 0; s < 2; ++s) {
      const unsigned short* vp = pVg + (size_t)(32 * s) * DM;
      unsigned L0 = *(const unsigned*)vp;
      unsigned L1 = *(const unsigned*)(vp + DM);
      unsigned L2 = *(const unsigned*)(vp + 2 * (size_t)DM);
      unsigned L3 = *(const unsigned*)(vp + 3 * (size_t)DM);
      ushort4 lo4, hi4;
      lo4.x = (unsigned short)L0; lo4.y = (unsigned short)L1;
      lo4.z = (unsigned short)L2; lo4.w = (unsigned short)L3;
      hi4.x = (unsigned short)(L0 >> 16); hi4.y = (unsigned short)(L1 >> 16);
      hi4.z = (unsigned short)(L2 >> 16); hi4.w = (unsigned short)(L3 >> 16);
      *(ushort4*)(vw0 + s * 2048) = lo4;
      *(ushort4*)(vw0 + s * 2048 + 8) = hi4;
    }
    pVg += (size_t)64 * DM;
    __syncthreads();  // drains vmcnt (K gl_lds) + lgkm (V writes) -> tiles valid

    // QK^T swapped: A = K rows, B = Q -> S^T; lane (c,quad) holds S[q=c][k slices]
    f32x4 sacc[4];
#pragma unroll
    for (int nt = 0; nt < 4; ++nt) {
#pragma unroll
      for (int r = 0; r < 4; ++r) sacc[nt][r] = 0.f;
      short8 ka = *(const short8*)(kf0 + nt * 1024);
      short8 kb = *(const short8*)(kf1 + nt * 1024);
      sacc[nt] = __builtin_amdgcn_mfma_f32_16x16x32_bf16(ka, qf[0], sacc[nt], 0, 0, 0);
      sacc[nt] = __builtin_amdgcn_mfma_f32_16x16x32_bf16(kb, qf[1], sacc[nt], 0, 0, 0);
    }

    // in-register softmax numerator (scores pre-scaled by 0.125*log2e via w_q)
    unsigned long long msh = bp[kt] >> shq;
    unsigned mlo = (unsigned)msh, mhi = (unsigned)(msh >> 32);
    unsigned padw[8];
#pragma unroll
    for (int nt = 0; nt < 4; ++nt) {
      unsigned msel = (nt & 2) ? mhi : mlo;
      const int bse = (nt & 1) * 16;
      float pv[4];
#pragma unroll
      for (int r = 0; r < 4; ++r) {
        float ex = fexp2(sacc[nt][r]);
        pv[r] = ((msel >> (bse + r)) & 1u) ? ex : 1.0f;  // masked -> exp(eps) ~ 1
      }
      padw[nt * 2] = cvtpk_bf16(pv[0], pv[1]);
      padw[nt * 2 + 1] = cvtpk_bf16(pv[2], pv[3]);
    }

    // PV: A = lane-local packed P (pi ordering), B = pi-permuted V fragments
#pragma unroll
    for (int pkt = 0; pkt < 2; ++pkt) {
      union { unsigned u[4]; short8 s8; } pa;
#pragma unroll
      for (int i = 0; i < 4; ++i) pa.u[i] = padw[pkt * 4 + i];
      lacc = __builtin_amdgcn_mfma_f32_16x16x32_bf16(pa.s8, ones8, lacc, 0, 0, 0);
#pragma unroll
      for (int dt = 0; dt < 4; ++dt) {
        short8 vf = *(const short8*)&VB[((pkt * 4 + dt) * 4 + quad) * 128 + c * 8];
        accO[dt] = __builtin_amdgcn_mfma_f32_16x16x32_bf16(pa.s8, vf, accO[dt], 0, 0, 0);
      }
    }
    __syncthreads();  // all waves done reading before next tile's staging
  }

  // lacc rows (quad*4+r) align with accO rows: direct normalize, no shuffles
  float inv[4];
#pragma unroll
  for (int r = 0; r < 4; ++r) inv[r] = 1.f / lacc[r];
#pragma unroll
  for (int dt = 0; dt < 4; ++dt)
#pragma unroll
    for (int r = 0; r < 4; ++r) {
      int q = q0 + w * 16 + quad * 4 + r;
      O[((size_t)b * SS + q) * DM + h * DK + dt * 16 + c] = f2bf(accO[dt][r] * inv[r]);
    }
}

// ---- Residual + LayerNorm (ddof=1, eps on std), vectorized ----
__global__ __launch_bounds__(256) void ln_k(const float* __restrict__ P,
                                            const float* __restrict__ X,
                                            const float* __restrict__ gamma,
                                            const float* __restrict__ beta,
                                            float* __restrict__ out) {
  __shared__ float sm[4];
  int row = blockIdx.x, tid = threadIdx.x, w = tid >> 6;
  float4 p = ((const float4*)(P + (size_t)row * DM))[tid];
  float4 x = ((const float4*)(X + (size_t)row * DM))[tid];
  float4 v = make_float4(p.x + x.x, p.y + x.y, p.z + x.z, p.w + x.w);
  float s = (v.x + v.y) + (v.z + v.w);
#pragma unroll
  for (int off = 1; off < 64; off <<= 1) s += __shfl_xor(s, off);
  if ((tid & 63) == 0) sm[w] = s;
  __syncthreads();
  float mean = (sm[0] + sm[1] + sm[2] + sm[3]) * (1.f / DM);
  __syncthreads();
  float dx = v.x - mean, dy = v.y - mean, dz = v.z - mean, dw = v.w - mean;
  float s2 = (dx * dx + dy * dy) + (dz * dz + dw * dw);
#pragma unroll
  for (int off = 1; off < 64; off <<= 1) s2 += __shfl_xor(s2, off);
  if ((tid & 63) == 0) sm[w] = s2;
  __syncthreads();
  float var = (sm[0] + sm[1] + sm[2] + sm[3]) * (1.f / (DM - 1));
  float inv = 1.f / (sqrtf(var) + EPSV);
  float4 g = ((const float4*)gamma)[tid];
  float4 be = ((const float4*)beta)[tid];
  float4 y = make_float4(g.x * dx * inv + be.x, g.y * dy * inv + be.y,
                         g.z * dz * inv + be.z, g.w * dw * inv + be.w);
  ((float4*)(out + (size_t)row * DM))[tid] = y;
}

extern "C" void kernel_launch(void* const* d_in, const int* in_sizes, int n_in,
                              void* d_out, int out_size, void* d_ws, size_t ws_size,
                              hipStream_t stream) {
  const float* xq = (const float*)d_in[0];
  const float* xk = (const float*)d_in[1];
  const float* xv = (const float*)d_in[2];
  const int* mask = (const int*)d_in[3];
  const float* wq = (const float*)d_in[4];
  const float* wk = (const float*)d_in[5];
  const float* wv = (const float*)d_in[6];
  const float* w0 = (const float*)d_in[7];
  const float* gamma = (const float*)d_in[8];
  const float* beta = (const float*)d_in[9];
  float* out = (float*)d_out;

  // ws: [xqb NE][xkb NE][xvb NE][wTq MM][wTk MM][wTv MM][wT0 MM][Qb NE][Kb NE][Vb NE][AOb NE]
  // P (f32, NE) overlays Qb+Kb (dead after attention).
  unsigned short* xqb = (unsigned short*)d_ws;
  unsigned short* xkb = xqb + NE;
  unsigned short* xvb = xkb + NE;
  unsigned short* wTq = xvb + NE;
  unsigned short* wTk = wTq + MM;
  unsigned short* wTv = wTk + MM;
  unsigned short* wT0 = wTv + MM;
  unsigned short* Qb = wT0 + MM;
  unsigned short* Kb = Qb + NE;
  unsigned short* Vb = Kb + NE;
  unsigned short* AOb = Vb + NE;
  float* P = (float*)Qb;
  unsigned long long* bm = (unsigned long long*)d_out;  // 2 MB, dead before ln_k writes

  const int M = BB * SS;  // 8192
  cvt_x_k<<<(unsigned)(3 * (NE / 4) / 256), 256, 0, stream>>>(xq, xk, xv, xqb, xkb, xvb);
  cvt_wT_k<<<dim3(32, 32, 4), 256, 0, stream>>>(wq, wk, wv, w0, wTq, wTk, wTv, wT0);
  maskbits_k<<<256, 256, 0, stream>>>(mask, bm);
  gemm_lds_k<true><<<dim3(DM / 128, M / 128, 3), 256, 0, stream>>>(
      xqb, wTq, Qb, M, DM, DM, NE, MM, NE);
  attn_mfma_k<<<dim3(SS / 64, NH, BB), 256, 0, stream>>>(Qb, Kb, Vb, bm, AOb);
  gemm_lds_k<false><<<dim3(DM / 128, M / 128, 1), 256, 0, stream>>>(
      AOb, wT0, P, M, DM, DM, 0, 0, 0);
  ln_k<<<M, 256, 0, stream>>>(P, xq, gamma, beta, out);
}

// Round 5
// 549.247 us; speedup vs baseline: 1.1026x; 1.0022x over previous
//
#include <hip/hip_runtime.h>
#include <hip/hip_bf16.h>
#include <math.h>

#define DM 1024
#define NH 16
#define DK 64
#define BB 4
#define SS 2048
#define EPSV 1e-6f
#define NE ((size_t)BB * SS * DM)  // 8388608
#define MM ((size_t)DM * DM)       // 1048576
// 0.125 * log2(e): folded into w_q so softmax is a raw exp2
#define QSCALE 0.18033688011112042f

typedef __attribute__((ext_vector_type(8))) short short8;
typedef __attribute__((ext_vector_type(4))) short short4v;
typedef __attribute__((ext_vector_type(4))) float f32x4;

__device__ inline unsigned short f2bf(float x) {
  unsigned int u = __builtin_bit_cast(unsigned int, x);
  u += 0x7FFF + ((u >> 16) & 1);  // RNE
  return (unsigned short)(u >> 16);
}
__device__ inline ushort4 f2bf4(float4 v) {
  ushort4 r;
  r.x = f2bf(v.x); r.y = f2bf(v.y); r.z = f2bf(v.z); r.w = f2bf(v.w);
  return r;
}

__device__ inline float fexp2(float x) {
#if __has_builtin(__builtin_amdgcn_exp2f)
  return __builtin_amdgcn_exp2f(x);
#else
  return exp2f(x);
#endif
}

// pack 2 f32 -> 1 dword of 2 bf16 (lo=a, hi=b)
__device__ inline unsigned cvtpk_bf16(float a, float b) {
  unsigned r;
  asm("v_cvt_pk_bf16_f32 %0, %1, %2" : "=v"(r) : "v"(a), "v"(b));
  return r;
}

// async global->LDS, 16B per lane; LDS dest = wave-uniform base + lane*16
__device__ inline void gl_lds16(const unsigned short* g, unsigned short* l) {
  __builtin_amdgcn_global_load_lds((const __attribute__((address_space(1))) void*)g,
                                   (__attribute__((address_space(3))) void*)l, 16, 0, 0);
}

// ---- Pre-pass: x tensors f32 -> bf16 (elementwise, float4) ----
__global__ __launch_bounds__(256) void cvt_x_k(const float* __restrict__ xq,
                                               const float* __restrict__ xk,
                                               const float* __restrict__ xv,
                                               unsigned short* __restrict__ oq,
                                               unsigned short* __restrict__ ok,
                                               unsigned short* __restrict__ ov) {
  const size_t NF4 = NE / 4;
  size_t g = (size_t)blockIdx.x * 256 + threadIdx.x;
  int t = (int)(g / NF4);
  size_t i = g - (size_t)t * NF4;
  const float* s = (t == 0) ? xq : (t == 1) ? xk : xv;
  unsigned short* d = (t == 0) ? oq : (t == 1) ? ok : ov;
  float4 v = ((const float4*)s)[i];
  ((ushort4*)d)[i] = f2bf4(v);
}

// ---- Pre-pass: W[k][n] f32 -> WT[n][k] bf16 (LDS transpose); w_q gets QSCALE ----
__global__ __launch_bounds__(256) void cvt_wT_k(const float* __restrict__ w0,
                                                const float* __restrict__ w1,
                                                const float* __restrict__ w2,
                                                const float* __restrict__ w3,
                                                unsigned short* __restrict__ o0,
                                                unsigned short* __restrict__ o1,
                                                unsigned short* __restrict__ o2,
                                                unsigned short* __restrict__ o3) {
  __shared__ float t[32][33];
  int z = blockIdx.z;
  const float* w = (z == 0) ? w0 : (z == 1) ? w1 : (z == 2) ? w2 : w3;
  unsigned short* o = (z == 0) ? o0 : (z == 1) ? o1 : (z == 2) ? o2 : o3;
  float sc = (z == 0) ? QSCALE : 1.0f;
  int n0 = blockIdx.x * 32, k0 = blockIdx.y * 32;
  int tx = threadIdx.x & 31, ty = threadIdx.x >> 5;
#pragma unroll
  for (int s = 0; s < 4; ++s) t[ty + s * 8][tx] = w[(size_t)(k0 + ty + s * 8) * DM + n0 + tx];
  __syncthreads();
#pragma unroll
  for (int s = 0; s < 4; ++s)
    o[(size_t)(n0 + ty + s * 8) * DM + k0 + tx] = f2bf(t[tx][ty + s * 8] * sc);
}

// ---- Pre-pass: pack int32 mask -> 1 bit ----
__global__ __launch_bounds__(256) void maskbits_k(const int* __restrict__ mask,
                                                  unsigned long long* __restrict__ bm) {
  const int total = BB * SS * (SS / 64);
  int lane = threadIdx.x & 63;
  int wid = (blockIdx.x * 256 + threadIdx.x) >> 6;
  int nw = (gridDim.x * 256) >> 6;
  for (int w = wid; w < total; w += nw) {
    int v = mask[(size_t)w * 64 + lane];
    unsigned long long bal = __ballot(v != 0);
    if (lane == 0) bm[w] = bal;
  }
}

// ---- V transpose: Vb[B,S,NH*DK] -> VT[B,NH,DK,S] (bf16, LDS tile) ----
__global__ __launch_bounds__(256) void vtrans_k(const unsigned short* __restrict__ Vb,
                                                unsigned short* __restrict__ VT) {
  __shared__ unsigned short t[64][72];
  int b = blockIdx.z, h = blockIdx.y, s0 = blockIdx.x * 64;
  int tid = threadIdx.x;
#pragma unroll
  for (int p = 0; p < 2; ++p) {
    int idx = p * 256 + tid;
    int r = idx >> 3, cch = (idx & 7) * 8;
    short8 v = *(const short8*)&Vb[((size_t)b * SS + s0 + r) * DM + h * DK + cch];
    *(short8*)&t[r][cch] = v;
  }
  __syncthreads();
#pragma unroll
  for (int p = 0; p < 2; ++p) {
    int idx = p * 256 + tid;
    int d = idx >> 3, sch = (idx & 7) * 8;
    union { short8 v; unsigned short u[8]; } pk;
#pragma unroll
    for (int j = 0; j < 8; ++j) pk.u[j] = t[sch + j][d];
    *(short8*)&VT[(((size_t)b * NH + h) * DK + d) * SS + s0 + sch] = pk.v;
  }
}

// ---- m97-style MFMA GEMM: C = A[M,K] @ WT[N,K]^T, bf16 in, 128x128 tile, BK=32.
template <bool BF16OUT>
__global__ __launch_bounds__(256) void gemm_lds_k(const unsigned short* __restrict__ Abase,
                                                  const unsigned short* __restrict__ WTbase,
                                                  void* __restrict__ Cv, int M, int N, int K,
                                                  size_t zA, size_t zW, size_t zC) {
  __shared__ __align__(16) unsigned short As[128 * 32];
  __shared__ __align__(16) unsigned short Bs[128 * 32];
  const unsigned short* A = Abase + (size_t)blockIdx.z * zA;
  const unsigned short* WT = WTbase + (size_t)blockIdx.z * zW;
  int bm = blockIdx.y * 128, bn = blockIdx.x * 128;
  int tid = threadIdx.x, lane = tid & 63, w = tid >> 6;
  int quad = lane >> 4, c = lane & 15, wx = w & 1, wy = w >> 1;

  f32x4 acc[4][4];
#pragma unroll
  for (int mt = 0; mt < 4; ++mt)
#pragma unroll
    for (int nt = 0; nt < 4; ++nt)
#pragma unroll
      for (int r = 0; r < 4; ++r) acc[mt][nt][r] = 0.f;

  int srow = lane >> 2, scol = (lane & 3) * 8;
  const unsigned short* Ag = A + (size_t)(bm + w * 32 + srow) * K + scol;
  const unsigned short* Bg = WT + (size_t)(bn + w * 32 + srow) * K + scol;
  unsigned short* Al = &As[w * 32 * 32];
  unsigned short* Bl = &Bs[w * 32 * 32];

  for (int k0 = 0; k0 < K; k0 += 32) {
    gl_lds16(Ag + k0, Al);
    gl_lds16(Ag + (size_t)16 * K + k0, Al + 16 * 32);
    gl_lds16(Bg + k0, Bl);
    gl_lds16(Bg + (size_t)16 * K + k0, Bl + 16 * 32);
    __syncthreads();  // drains vmcnt -> LDS valid
    short8 af[4], bf[4];
#pragma unroll
    for (int mt = 0; mt < 4; ++mt) af[mt] = *(const short8*)&As[(wy * 64 + mt * 16 + c) * 32 + quad * 8];
#pragma unroll
    for (int nt = 0; nt < 4; ++nt) bf[nt] = *(const short8*)&Bs[(wx * 64 + nt * 16 + c) * 32 + quad * 8];
#pragma unroll
    for (int mt = 0; mt < 4; ++mt)
#pragma unroll
      for (int nt = 0; nt < 4; ++nt)
        acc[mt][nt] = __builtin_amdgcn_mfma_f32_16x16x32_bf16(af[mt], bf[nt], acc[mt][nt], 0, 0, 0);
    __syncthreads();
  }
#pragma unroll
  for (int mt = 0; mt < 4; ++mt)
#pragma unroll
    for (int nt = 0; nt < 4; ++nt)
#pragma unroll
      for (int r = 0; r < 4; ++r) {
        size_t idx = (size_t)blockIdx.z * zC +
                     (size_t)(bm + wy * 64 + mt * 16 + quad * 4 + r) * N + bn + wx * 64 + nt * 16 + c;
        if (BF16OUT)
          ((unsigned short*)Cv)[idx] = f2bf(acc[mt][nt][r]);
        else
          ((float*)Cv)[idx] = acc[mt][nt][r];
      }
}

// ---- MFMA flash attention, swapped-QK^T, double-buffered gl_lds staging.
// K LDS: row-major [64][8 chunks of 8], chunk XOR (cc ^ (row&7)) pre-applied to
//        the GLOBAL source (R4-verified); ds_read_b128 applies the same XOR.
// V via VT[b][h][d][s]: staged identically to K (rows = d). PV B-fragment slot m
//        needs k = sigma(m) = 16*((m&7)>>2) + 4*(m>>3) + (m&3)  (derived from the
//        R4-proven VB content): two 8B runs per fragment, second = first ^16 elems.
//        Lanes c and c+8 read identical addrs (broadcast) -> ~conflict-free.
// 2-phase pipeline: barrier -> prefetch(next, other buf) -> compute(cur).
// Row-sum via ones-MFMA: lacc rows (quad*4+r) align with accO rows.
__global__ __launch_bounds__(256) void attn_mfma_k(const unsigned short* __restrict__ Q,
                                                   const unsigned short* __restrict__ Kg,
                                                   const unsigned short* __restrict__ VT,
                                                   const unsigned long long* __restrict__ bm,
                                                   unsigned short* __restrict__ O) {
  __shared__ __align__(16) unsigned short Ks[2][64 * 64];
  __shared__ __align__(16) unsigned short Vs[2][64 * 64];
  int b = blockIdx.z, h = blockIdx.y, q0 = blockIdx.x * 64;
  int tid = threadIdx.x, lane = tid & 63, w = tid >> 6;
  int quad = lane >> 4, c = lane & 15;

  short8 qf[2];
  {
    const unsigned short* qp = Q + ((size_t)b * SS + q0 + w * 16 + c) * DM + h * DK + quad * 8;
    qf[0] = *(const short8*)qp;
    qf[1] = *(const short8*)(qp + 32);
  }
  const unsigned long long* bp = bm + ((size_t)b * SS + q0 + w * 16 + c) * (SS / 64);
  const int shq = quad * 4;

  short8 ones8;
#pragma unroll
  for (int j = 0; j < 8; ++j) ones8[j] = (short)0x3F80;  // bf16 1.0

  f32x4 accO[4], lacc;
#pragma unroll
  for (int r = 0; r < 4; ++r) lacc[r] = 0.f;
#pragma unroll
  for (int dt = 0; dt < 4; ++dt)
#pragma unroll
    for (int r = 0; r < 4; ++r) accO[dt][r] = 0.f;

  // K staging source (R4-verified): chunk n=tid (+256): row n>>3, grp (n&7)^(row&7)
  int kr = tid >> 3;
  int scc = (tid & 7) ^ (kr & 7);
  const unsigned short* pK0 = Kg + ((size_t)b * SS + kr) * DM + h * DK + scc * 8;
  const unsigned short* pK1 = pK0 + (size_t)32 * DM;
  // VT staging source: rows = d (kr), cols = s (advance 64/tile), same XOR
  const unsigned short* pV0 = VT + (((size_t)b * NH + h) * DK + kr) * SS + scc * 8;
  const unsigned short* pV1 = pV0 + (size_t)32 * SS;

  // QK fragment elem offsets (row c + nt*16; row&7 == c&7): logical chunk g -> g^(c&7)
  const int kfo0 = c * 64 + ((quad ^ (c & 7)) * 8);
  const int kfo1 = c * 64 + (((4 + quad) ^ (c & 7)) * 8);
  // PV fragment elem offsets: row c + dt*16; piece1 chunk pkt*4+(quad>>1), +(quad&1)*4
  const int vfo0 = c * 64 + ((((quad >> 1)) ^ (c & 7)) * 8) + (quad & 1) * 4;        // pkt0
  const int vfo1 = c * 64 + (((4 + (quad >> 1)) ^ (c & 7)) * 8) + (quad & 1) * 4;    // pkt1

  const int NT = SS / 64;

  // prologue: stage tile 0 into buf 0
  gl_lds16(pK0, &Ks[0][w * 512]);
  gl_lds16(pK1, &Ks[0][2048 + w * 512]);
  gl_lds16(pV0, &Vs[0][w * 512]);
  gl_lds16(pV1, &Vs[0][2048 + w * 512]);
  pK0 += (size_t)64 * DM; pK1 += (size_t)64 * DM;
  pV0 += 64; pV1 += 64;

  auto tile = [&](int buf, int kt) {
    __syncthreads();  // drains vmcnt: tile kt ready; all waves done with buf^1
    if (kt + 1 < NT) {
      gl_lds16(pK0, &Ks[buf ^ 1][w * 512]);
      gl_lds16(pK1, &Ks[buf ^ 1][2048 + w * 512]);
      gl_lds16(pV0, &Vs[buf ^ 1][w * 512]);
      gl_lds16(pV1, &Vs[buf ^ 1][2048 + w * 512]);
      pK0 += (size_t)64 * DM; pK1 += (size_t)64 * DM;
      pV0 += 64; pV1 += 64;
    }

    // QK^T swapped: A = K rows, B = Q -> S^T; lane (c,quad) holds S[q=c][k slices]
    f32x4 sacc[4];
#pragma unroll
    for (int nt = 0; nt < 4; ++nt) {
#pragma unroll
      for (int r = 0; r < 4; ++r) sacc[nt][r] = 0.f;
      short8 ka = *(const short8*)&Ks[buf][kfo0 + nt * 1024];
      short8 kb = *(const short8*)&Ks[buf][kfo1 + nt * 1024];
      sacc[nt] = __builtin_amdgcn_mfma_f32_16x16x32_bf16(ka, qf[0], sacc[nt], 0, 0, 0);
      sacc[nt] = __builtin_amdgcn_mfma_f32_16x16x32_bf16(kb, qf[1], sacc[nt], 0, 0, 0);
    }

    // in-register softmax numerator (scores pre-scaled by 0.125*log2e via w_q)
    unsigned long long msh = bp[kt] >> shq;
    unsigned mlo = (unsigned)msh, mhi = (unsigned)(msh >> 32);
    unsigned padw[8];
#pragma unroll
    for (int nt = 0; nt < 4; ++nt) {
      unsigned msel = (nt & 2) ? mhi : mlo;
      const int bse = (nt & 1) * 16;
      float pv[4];
#pragma unroll
      for (int r = 0; r < 4; ++r) {
        float ex = fexp2(sacc[nt][r]);
        pv[r] = ((msel >> (bse + r)) & 1u) ? ex : 1.0f;  // masked -> exp(eps) ~ 1
      }
      padw[nt * 2] = cvtpk_bf16(pv[0], pv[1]);
      padw[nt * 2 + 1] = cvtpk_bf16(pv[2], pv[3]);
    }

    // PV: A = lane-local packed P, B = VT fragments (two 8B pieces each)
#pragma unroll
    for (int pkt = 0; pkt < 2; ++pkt) {
      union { unsigned u[4]; short8 s8; } pa;
#pragma unroll
      for (int i = 0; i < 4; ++i) pa.u[i] = padw[pkt * 4 + i];
      lacc = __builtin_amdgcn_mfma_f32_16x16x32_bf16(pa.s8, ones8, lacc, 0, 0, 0);
      const int vfo = pkt ? vfo1 : vfo0;
#pragma unroll
      for (int dt = 0; dt < 4; ++dt) {
        int e1 = vfo + dt * 1024;
        union { short4v h[2]; short8 s8; } vf;
        vf.h[0] = *(const short4v*)&Vs[buf][e1];
        vf.h[1] = *(const short4v*)&Vs[buf][e1 ^ 16];
        accO[dt] = __builtin_amdgcn_mfma_f32_16x16x32_bf16(pa.s8, vf.s8, accO[dt], 0, 0, 0);
      }
    }
  };

  for (int kt2 = 0; kt2 < NT; kt2 += 2) {
    tile(0, kt2);
    tile(1, kt2 + 1);
  }

  // lacc rows (quad*4+r) align with accO rows: direct normalize, no shuffles
  float inv[4];
#pragma unroll
  for (int r = 0; r < 4; ++r) inv[r] = 1.f / lacc[r];
#pragma unroll
  for (int dt = 0; dt < 4; ++dt)
#pragma unroll
    for (int r = 0; r < 4; ++r) {
      int q = q0 + w * 16 + quad * 4 + r;
      O[((size_t)b * SS + q) * DM + h * DK + dt * 16 + c] = f2bf(accO[dt][r] * inv[r]);
    }
}

// ---- Residual + LayerNorm (ddof=1, eps on std), vectorized ----
__global__ __launch_bounds__(256) void ln_k(const float* __restrict__ P,
                                            const float* __restrict__ X,
                                            const float* __restrict__ gamma,
                                            const float* __restrict__ beta,
                                            float* __restrict__ out) {
  __shared__ float sm[4];
  int row = blockIdx.x, tid = threadIdx.x, w = tid >> 6;
  float4 p = ((const float4*)(P + (size_t)row * DM))[tid];
  float4 x = ((const float4*)(X + (size_t)row * DM))[tid];
  float4 v = make_float4(p.x + x.x, p.y + x.y, p.z + x.z, p.w + x.w);
  float s = (v.x + v.y) + (v.z + v.w);
#pragma unroll
  for (int off = 1; off < 64; off <<= 1) s += __shfl_xor(s, off);
  if ((tid & 63) == 0) sm[w] = s;
  __syncthreads();
  float mean = (sm[0] + sm[1] + sm[2] + sm[3]) * (1.f / DM);
  __syncthreads();
  float dx = v.x - mean, dy = v.y - mean, dz = v.z - mean, dw = v.w - mean;
  float s2 = (dx * dx + dy * dy) + (dz * dz + dw * dw);
#pragma unroll
  for (int off = 1; off < 64; off <<= 1) s2 += __shfl_xor(s2, off);
  if ((tid & 63) == 0) sm[w] = s2;
  __syncthreads();
  float var = (sm[0] + sm[1] + sm[2] + sm[3]) * (1.f / (DM - 1));
  float inv = 1.f / (sqrtf(var) + EPSV);
  float4 g = ((const float4*)gamma)[tid];
  float4 be = ((const float4*)beta)[tid];
  float4 y = make_float4(g.x * dx * inv + be.x, g.y * dy * inv + be.y,
                         g.z * dz * inv + be.z, g.w * dw * inv + be.w);
  ((float4*)(out + (size_t)row * DM))[tid] = y;
}

extern "C" void kernel_launch(void* const* d_in, const int* in_sizes, int n_in,
                              void* d_out, int out_size, void* d_ws, size_t ws_size,
                              hipStream_t stream) {
  const float* xq = (const float*)d_in[0];
  const float* xk = (const float*)d_in[1];
  const float* xv = (const float*)d_in[2];
  const int* mask = (const int*)d_in[3];
  const float* wq = (const float*)d_in[4];
  const float* wk = (const float*)d_in[5];
  const float* wv = (const float*)d_in[6];
  const float* w0 = (const float*)d_in[7];
  const float* gamma = (const float*)d_in[8];
  const float* beta = (const float*)d_in[9];
  float* out = (float*)d_out;

  // ws: [xqb NE][xkb NE][xvb NE][wTq MM][wTk MM][wTv MM][wT0 MM][Qb NE][Kb NE][Vb NE][AOb NE]
  // P (f32, NE) overlays Qb+Kb (dead after attention).
  // VT (bf16, NE) overlays xvb (dead after the QKV GEMM).
  unsigned short* xqb = (unsigned short*)d_ws;
  unsigned short* xkb = xqb + NE;
  unsigned short* xvb = xkb + NE;
  unsigned short* wTq = xvb + NE;
  unsigned short* wTk = wTq + MM;
  unsigned short* wTv = wTk + MM;
  unsigned short* wT0 = wTv + MM;
  unsigned short* Qb = wT0 + MM;
  unsigned short* Kb = Qb + NE;
  unsigned short* Vb = Kb + NE;
  unsigned short* AOb = Vb + NE;
  unsigned short* VTb = xvb;  // overlay
  float* P = (float*)Qb;
  unsigned long long* bm = (unsigned long long*)d_out;  // 2 MB, dead before ln_k writes

  const int M = BB * SS;  // 8192
  cvt_x_k<<<(unsigned)(3 * (NE / 4) / 256), 256, 0, stream>>>(xq, xk, xv, xqb, xkb, xvb);
  cvt_wT_k<<<dim3(32, 32, 4), 256, 0, stream>>>(wq, wk, wv, w0, wTq, wTk, wTv, wT0);
  maskbits_k<<<256, 256, 0, stream>>>(mask, bm);
  gemm_lds_k<true><<<dim3(DM / 128, M / 128, 3), 256, 0, stream>>>(
      xqb, wTq, Qb, M, DM, DM, NE, MM, NE);
  vtrans_k<<<dim3(SS / 64, NH, BB), 256, 0, stream>>>(Vb, VTb);
  attn_mfma_k<<<dim3(SS / 64, NH, BB), 256, 0, stream>>>(Qb, Kb, VTb, bm, AOb);
  gemm_lds_k<false><<<dim3(DM / 128, M / 128, 1), 256, 0, stream>>>(
      AOb, wT0, P, M, DM, DM, 0, 0, 0);
  ln_k<<<M, 256, 0, stream>>>(P, xq, gamma, beta, out);
}